// Round 5
// baseline (3064.198 us; speedup 1.0000x reference)
//
#include <hip/hip_runtime.h>
#include <math.h>

#define NDIM 128   // in_dim = hid = out_dim
#define H2   256   // 2*hid
#define MAXG 2
#define TPE  8192  // edges per bin tile
#define NBKMAX 512 // max dst/src buckets (N <= 65536, 128 nodes/bucket)

typedef __attribute__((ext_vector_type(8))) short bf16x8;
typedef __attribute__((ext_vector_type(4))) float f32x4;

__device__ __forceinline__ unsigned short f2bf(float f) {
    unsigned int u = __float_as_uint(f);
    u += 0x7fffu + ((u >> 16) & 1u);           // RNE
    return (unsigned short)(u >> 16);
}
__device__ __forceinline__ float bf2f(unsigned short h) {
    return __uint_as_float(((unsigned int)h) << 16);
}
__device__ __forceinline__ void split2(float f, unsigned short& h, unsigned short& l) {
    h = f2bf(f);
    l = f2bf(f - bf2f(h));
}

// ================= binned edge build (no global atomics) =================
struct BinArgs {
    const int* src[MAXG]; const int* dst[MAXG];
    int* histD[MAXG]; int* histS[MAXG];     // [NT][NBK] counts -> global offsets
    int* totD[MAXG];  int* baseD[MAXG];
    int* totS[MAXG];  int* baseS[MAXG];
    unsigned int* pairs[MAXG];              // dst-binned packed (dl<<16|src)
    unsigned short* srcS[MAXG];             // src-binned bare src ids
    float* ns[MAXG]; float* nd[MAXG];
    int E[MAXG]; int NBK; int NT; int n;
};

// per-tile bucket histograms (LDS), coalesced flush
__global__ __launch_bounds__(256) void binA(BinArgs a) {
    __shared__ int cntD[NBKMAX], cntS[NBKMAX];
    int g = blockIdx.y, t = blockIdx.x, tid = threadIdx.x;
    for (int b = tid; b < NBKMAX; b += 256) { cntD[b] = 0; cntS[b] = 0; }
    __syncthreads();
    int E = a.E[g];
    int base = t * TPE;
#pragma unroll
    for (int k = 0; k < TPE / 256; ++k) {
        int e = base + k * 256 + tid;
        if (e < E) {
            atomicAdd(&cntD[a.dst[g][e] >> 7], 1);
            atomicAdd(&cntS[a.src[g][e] >> 7], 1);
        }
    }
    __syncthreads();
    for (int b = tid; b < a.NBK; b += 256) {
        a.histD[g][t * a.NBK + b] = cntD[b];
        a.histS[g][t * a.NBK + b] = cntS[b];
    }
}

// per-bucket totals over tiles
__global__ void binB1(BinArgs a) {
    int g = blockIdx.y, side = blockIdx.z;
    int b = blockIdx.x * 256 + threadIdx.x;
    if (b >= a.NBK) return;
    const int* hist = side ? a.histS[g] : a.histD[g];
    int s = 0;
    for (int t = 0; t < a.NT; ++t) s += hist[t * a.NBK + b];
    (side ? a.totS[g] : a.totD[g])[b] = s;
}

// exclusive scan of bucket totals -> bases (NBK <= 512)
__global__ __launch_bounds__(512) void binB2(BinArgs a) {
    int g = blockIdx.y, side = blockIdx.z;
    __shared__ int s[512];
    int t = threadIdx.x;
    const int* tot = side ? a.totS[g] : a.totD[g];
    int v = (t < a.NBK) ? tot[t] : 0;
    s[t] = v;
    __syncthreads();
    for (int off = 1; off < 512; off <<= 1) {
        int u = (t >= off) ? s[t - off] : 0;
        __syncthreads();
        s[t] += u;
        __syncthreads();
    }
    if (t < a.NBK) (side ? a.baseS[g] : a.baseD[g])[t] = s[t] - v;
}

// rewrite hist[t][b] -> global run offset = base[b] + prefix_t
__global__ void binB3(BinArgs a) {
    int g = blockIdx.y, side = blockIdx.z;
    int b = blockIdx.x * 64 + threadIdx.x;
    if (b >= a.NBK) return;
    int* hist = side ? a.histS[g] : a.histD[g];
    int run = (side ? a.baseS[g] : a.baseD[g])[b];
    for (int t = 0; t < a.NT; ++t) {
        int v = hist[t * a.NBK + b];
        hist[t * a.NBK + b] = run;
        run += v;
    }
}

// scatter edges into bucket segments (deterministic offsets, LDS slot counters)
__global__ __launch_bounds__(256) void binC(BinArgs a) {
    __shared__ int offD[NBKMAX], offS[NBKMAX];
    int g = blockIdx.y, t = blockIdx.x, tid = threadIdx.x;
    for (int b = tid; b < a.NBK; b += 256) {
        offD[b] = a.histD[g][t * a.NBK + b];
        offS[b] = a.histS[g][t * a.NBK + b];
    }
    __syncthreads();
    int E = a.E[g];
    int base = t * TPE;
    unsigned int* pairs = a.pairs[g];
    unsigned short* ss = a.srcS[g];
#pragma unroll
    for (int k = 0; k < TPE / 256; ++k) {
        int e = base + k * 256 + tid;
        if (e < E) {
            int s = a.src[g][e], d = a.dst[g][e];
            int pos = atomicAdd(&offD[d >> 7], 1);
            pairs[pos] = ((unsigned int)(d & 127) << 16) | (unsigned int)s;
            int posS = atomicAdd(&offS[s >> 7], 1);
            ss[posS] = (unsigned short)s;
        }
    }
}

// exact out-degree per node via per-bucket LDS histogram -> norm_src
__global__ __launch_bounds__(256) void srchist(BinArgs a) {
    __shared__ int cnt[128];
    int g = blockIdx.y, b = blockIdx.x, tid = threadIdx.x;
    if (tid < 128) cnt[tid] = 0;
    __syncthreads();
    int base = a.baseS[g][b], tot = a.totS[g][b];
    const unsigned short* ss = a.srcS[g];
    for (int i = tid; i < tot; i += 256)
        atomicAdd(&cnt[ss[base + i] & 127], 1);
    __syncthreads();
    if (tid < 128) {
        int node = b * 128 + tid;
        if (node < a.n) {
            int c = cnt[tid];
            a.ns[g][node] = rsqrtf((float)(c > 1 ? c : 1));
        }
    }
}

// ================= LDS-accumulated gather-aggregate =================
// block = one 128-node dst bucket; 16 waves stream packed pairs; fp32 accum in LDS.
// LAYER 1: out = split(sum X[s]*ns[s]); also computes deg_in -> nd.
// LAYER 2: out = split(relu(sum * nd[row] + bias[col])).
struct GatherArgs {
    const float* X[MAXG];
    const unsigned int* pairs[MAXG];
    const int* totD[MAXG]; const int* baseD[MAXG];
    const float* ns[MAXG]; float* nd[MAXG];
    unsigned short* outH[MAXG]; unsigned short* outL[MAXG];
    const float* bias; int n;
};

template <int LAYER>
__global__ __launch_bounds__(1024) void gather_lds(GatherArgs a) {
    __shared__ float acc[128 * 128];
    __shared__ int degc[128];
    __shared__ float sh_nd[128];
    __shared__ float sh_b[128];
    int g = blockIdx.y, bkt = blockIdx.x, tid = threadIdx.x;

    for (int k = tid; k < 16384; k += 1024) acc[k] = 0.f;
    if (LAYER == 1) {
        if (tid < 128) degc[tid] = 0;
    } else {
        if (tid < 128) {
            int node = bkt * 128 + tid;
            sh_nd[tid] = (node < a.n) ? a.nd[g][node] : 0.f;
            sh_b[tid] = a.bias[tid];
        }
    }
    __syncthreads();

    int cnt = a.totD[g][bkt];
    const unsigned int* pp = a.pairs[g] + a.baseD[g][bkt];
    const float* X = a.X[g];
    const float* ns = a.ns[g];
    int w = tid >> 6, lane = tid & 63;

    int i = w;
    for (; i + 16 < cnt; i += 32) {
        unsigned int p0 = pp[i], p1 = pp[i + 16];
        int s0 = p0 & 0xFFFF, dl0 = p0 >> 16;
        int s1 = p1 & 0xFFFF, dl1 = p1 >> 16;
        float c0 = ns[s0], c1 = ns[s1];
        float2 v0 = *(const float2*)(X + (size_t)s0 * NDIM + lane * 2);
        float2 v1 = *(const float2*)(X + (size_t)s1 * NDIM + lane * 2);
        float* a0 = acc + dl0 * 128 + lane * 2;
        float* a1 = acc + dl1 * 128 + lane * 2;
        atomicAdd(a0, v0.x * c0); atomicAdd(a0 + 1, v0.y * c0);
        atomicAdd(a1, v1.x * c1); atomicAdd(a1 + 1, v1.y * c1);
        if (LAYER == 1 && lane == 0) { atomicAdd(&degc[dl0], 1); atomicAdd(&degc[dl1], 1); }
    }
    if (i < cnt) {
        unsigned int p0 = pp[i];
        int s0 = p0 & 0xFFFF, dl0 = p0 >> 16;
        float c0 = ns[s0];
        float2 v0 = *(const float2*)(X + (size_t)s0 * NDIM + lane * 2);
        float* a0 = acc + dl0 * 128 + lane * 2;
        atomicAdd(a0, v0.x * c0); atomicAdd(a0 + 1, v0.y * c0);
        if (LAYER == 1 && lane == 0) atomicAdd(&degc[dl0], 1);
    }
    __syncthreads();

    if (LAYER == 1 && tid < 128) {
        int node = bkt * 128 + tid;
        if (node < a.n) {
            int d = degc[tid];
            a.nd[g][node] = rsqrtf((float)(d > 1 ? d : 1));
        }
    }

    for (int k = tid; k < 16384; k += 1024) {
        int row = k >> 7, col = k & 127;
        int node = bkt * 128 + row;
        if (node >= a.n) continue;
        float v = acc[k];
        if (LAYER == 2) v = fmaxf(v * sh_nd[row] + sh_b[col], 0.f);
        unsigned short h, l;
        split2(v, h, l);
        a.outH[g][(size_t)node * NDIM + col] = h;
        a.outL[g][(size_t)node * NDIM + col] = l;
    }
}

// ================= weight prep: all 4 weights, transposed + split =================
__global__ void wprep_all(const float* __restrict__ W1, const float* __restrict__ W2,
                          const float* __restrict__ F1, const float* __restrict__ F2,
                          unsigned short* __restrict__ W1h, unsigned short* __restrict__ W1l,
                          unsigned short* __restrict__ W2h, unsigned short* __restrict__ W2l,
                          unsigned short* __restrict__ F1h, unsigned short* __restrict__ F1l,
                          unsigned short* __restrict__ F2h, unsigned short* __restrict__ F2l) {
    int i = blockIdx.x * 256 + threadIdx.x;
    const float* Wsrc; unsigned short *Hd, *Ld; int K, Nc, idx;
    if (i < 32768)       { Wsrc = W1; Hd = W1h; Ld = W1l; K = 128; Nc = 256; idx = i; }
    else if (i < 65536)  { Wsrc = W2; Hd = W2h; Ld = W2l; K = 256; Nc = 128; idx = i - 32768; }
    else if (i < 81920)  { Wsrc = F1; Hd = F1h; Ld = F1l; K = 128; Nc = 128; idx = i - 65536; }
    else                 { Wsrc = F2; Hd = F2h; Ld = F2l; K = 128; Nc = 128; idx = i - 81920; }
    int k = idx / Nc, n = idx % Nc;
    unsigned short h, l;
    split2(Wsrc[idx], h, l);
    Hd[n * K + k] = h;
    Ld[n * K + k] = l;
}

// ================= split-bf16 MFMA GEMM (batched via blockIdx.z) =================
struct GemmArgs {
    const unsigned short* Ah[MAXG]; const unsigned short* Al[MAXG];
    const unsigned short* Bh; const unsigned short* Bl;
    float* C[MAXG]; unsigned short* CH[MAXG]; unsigned short* CL[MAXG];
    const float* rsOut[MAXG]; const float* bOut;
    int M, K, Nc, act, has_rs, has_b, split_out;
};

__global__ __launch_bounds__(256) void mfma_gemm_b(GemmArgs a) {
    __shared__ __align__(16) unsigned short Ah[64 * 40];
    __shared__ __align__(16) unsigned short Al[64 * 40];
    __shared__ __align__(16) unsigned short Bh[128 * 40];
    __shared__ __align__(16) unsigned short Bl[128 * 40];

    int g = blockIdx.z;
    const unsigned short* Ah_g = a.Ah[g];
    const unsigned short* Al_g = a.Al[g];

    int tid  = threadIdx.x;
    int wave = tid >> 6, lane = tid & 63;
    int quad = lane >> 4, l16 = lane & 15;
    int rowBase = blockIdx.x * 64;
    int colBase = blockIdx.y * 128;
    int M = a.M, K = a.K, Nc = a.Nc;

    f32x4 acc[4][2] = {};

    int s_row   = tid >> 2;
    int s_chunk = (tid & 3) * 8;

    for (int k0 = 0; k0 < K; k0 += 32) {
        int gr = rowBase + s_row;
        uint4 va_h = make_uint4(0, 0, 0, 0), va_l = make_uint4(0, 0, 0, 0);
        if (gr < M) {
            va_h = *(const uint4*)(Ah_g + (size_t)gr * K + k0 + s_chunk);
            va_l = *(const uint4*)(Al_g + (size_t)gr * K + k0 + s_chunk);
        }
        *(uint4*)(Ah + s_row * 40 + s_chunk) = va_h;
        *(uint4*)(Al + s_row * 40 + s_chunk) = va_l;
#pragma unroll
        for (int c = tid; c < 512; c += 256) {
            int bn = c >> 2, bc = (c & 3) * 8;
            uint4 vb_h = *(const uint4*)(a.Bh + (size_t)(colBase + bn) * K + k0 + bc);
            uint4 vb_l = *(const uint4*)(a.Bl + (size_t)(colBase + bn) * K + k0 + bc);
            *(uint4*)(Bh + bn * 40 + bc) = vb_h;
            *(uint4*)(Bl + bn * 40 + bc) = vb_l;
        }
        __syncthreads();

        bf16x8 af[4], alf[4], bhf[2], blf[2];
#pragma unroll
        for (int i = 0; i < 4; ++i) {
            af[i]  = *(const bf16x8*)(Ah + (i * 16 + l16) * 40 + quad * 8);
            alf[i] = *(const bf16x8*)(Al + (i * 16 + l16) * 40 + quad * 8);
        }
#pragma unroll
        for (int j = 0; j < 2; ++j) {
            bhf[j] = *(const bf16x8*)(Bh + (wave * 32 + j * 16 + l16) * 40 + quad * 8);
            blf[j] = *(const bf16x8*)(Bl + (wave * 32 + j * 16 + l16) * 40 + quad * 8);
        }
#pragma unroll
        for (int i = 0; i < 4; ++i)
#pragma unroll
            for (int j = 0; j < 2; ++j) {
                acc[i][j] = __builtin_amdgcn_mfma_f32_16x16x32_bf16(af[i],  bhf[j], acc[i][j], 0, 0, 0);
                acc[i][j] = __builtin_amdgcn_mfma_f32_16x16x32_bf16(alf[i], bhf[j], acc[i][j], 0, 0, 0);
                acc[i][j] = __builtin_amdgcn_mfma_f32_16x16x32_bf16(af[i],  blf[j], acc[i][j], 0, 0, 0);
            }
        __syncthreads();
    }

    // epilogue: C/D layout col=lane&15, row=quad*4+reg
#pragma unroll
    for (int i = 0; i < 4; ++i) {
#pragma unroll
        for (int r = 0; r < 4; ++r) {
            int row = rowBase + i * 16 + quad * 4 + r;
            if (row >= M) continue;
            float rs = a.has_rs ? a.rsOut[g][row] : 1.0f;
#pragma unroll
            for (int j = 0; j < 2; ++j) {
                int col = colBase + wave * 32 + j * 16 + l16;
                float v = acc[i][j][r] * rs;
                if (a.has_b) v += a.bOut[col];
                if (a.act == 1) v = fmaxf(v, 0.f);
                else if (a.act == 2) v = v > 0.f ? v : expm1f(v);
                if (a.split_out) {
                    unsigned short h, l;
                    split2(v, h, l);
                    a.CH[g][(size_t)row * Nc + col] = h;
                    a.CL[g][(size_t)row * Nc + col] = l;
                } else {
                    a.C[g][(size_t)row * Nc + col] = v;
                }
            }
        }
    }
}

extern "C" void kernel_launch(void* const* d_in, const int* in_sizes, int n_in,
                              void* d_out, int out_size, void* d_ws, size_t ws_size,
                              hipStream_t stream) {
    const float* feat[2] = {(const float*)d_in[0], (const float*)d_in[1]};
    const int*   ei[2]   = {(const int*)d_in[2], (const int*)d_in[3]};
    const float* W1   = (const float*)d_in[4];
    const float* b1   = (const float*)d_in[5];
    const float* W2   = (const float*)d_in[6];
    const float* b2   = (const float*)d_in[7];
    const float* fc1W = (const float*)d_in[8];
    const float* fc1b = (const float*)d_in[9];
    const float* fc2W = (const float*)d_in[10];
    const float* fc2b = (const float*)d_in[11];
    int N = in_sizes[0] / NDIM;     // 50000 (< 65536: u16 node-id packing valid)
    float* out = (float*)d_out;

    int Emax = 0;
    for (int g = 0; g < 2; ++g) { int E = in_sizes[2 + g] / 2; if (E > Emax) Emax = E; }
    int NBK = (N + 127) / 128;
    int NT  = (Emax + TPE - 1) / TPE;

    // ---- workspace layout ----
    char* p = (char*)d_ws;
    float* ns_[2]; float* nd_[2];
    for (int i = 0; i < 2; ++i) { ns_[i] = (float*)p; p += (size_t)N * 4; }
    for (int i = 0; i < 2; ++i) { nd_[i] = (float*)p; p += (size_t)N * 4; }
    unsigned int* pairs_[2];
    for (int i = 0; i < 2; ++i) { pairs_[i] = (unsigned int*)p; p += (size_t)Emax * 4; }
    unsigned short* R1[2]; unsigned short* R2[2];
    for (int i = 0; i < 2; ++i) { R1[i] = (unsigned short*)p; p += (size_t)N * NDIM * 2 * 2; }
    for (int i = 0; i < 2; ++i) { R2[i] = (unsigned short*)p; p += (size_t)N * H2 * 2 * 2; }
    unsigned short* W1th = (unsigned short*)p; p += (size_t)NDIM * H2 * 2;
    unsigned short* W1tl = (unsigned short*)p; p += (size_t)NDIM * H2 * 2;
    unsigned short* W2th = (unsigned short*)p; p += (size_t)H2 * NDIM * 2;
    unsigned short* W2tl = (unsigned short*)p; p += (size_t)H2 * NDIM * 2;
    unsigned short* f1th = (unsigned short*)p; p += (size_t)NDIM * NDIM * 2;
    unsigned short* f1tl = (unsigned short*)p; p += (size_t)NDIM * NDIM * 2;
    unsigned short* f2th = (unsigned short*)p; p += (size_t)NDIM * NDIM * 2;
    unsigned short* f2tl = (unsigned short*)p; p += (size_t)NDIM * NDIM * 2;
    int* tb = (int*)p; p += (size_t)2 * 4 * NBK * 4;   // totD/baseD/totS/baseS per graph

    // aliases with disjoint lifetimes:
    //  - hist tables live only until binC; R2 first written by gemm1 (after binC)
    //  - srcS lives only until srchist; R1 first written by gather1 (after srchist)
    int* histD_[2]; int* histS_[2]; unsigned short* srcS_[2];
    for (int i = 0; i < 2; ++i) {
        histD_[i] = (int*)R2[i];
        histS_[i] = (int*)R2[i] + (size_t)NT * NBK;
        srcS_[i]  = (unsigned short*)R1[i];
    }

    BinArgs ba = {};
    ba.NBK = NBK; ba.NT = NT; ba.n = N;
    for (int i = 0; i < 2; ++i) {
        int E = in_sizes[2 + i] / 2;
        ba.src[i] = ei[i]; ba.dst[i] = ei[i] + E; ba.E[i] = E;
        ba.histD[i] = histD_[i]; ba.histS[i] = histS_[i];
        ba.totD[i]  = tb + (size_t)i * 4 * NBK;
        ba.baseD[i] = tb + (size_t)i * 4 * NBK + NBK;
        ba.totS[i]  = tb + (size_t)i * 4 * NBK + 2 * NBK;
        ba.baseS[i] = tb + (size_t)i * 4 * NBK + 3 * NBK;
        ba.pairs[i] = pairs_[i]; ba.srcS[i] = srcS_[i];
        ba.ns[i] = ns_[i]; ba.nd[i] = nd_[i];
    }

    // ---- weight prep + binned edge build ----
    wprep_all<<<384, 256, 0, stream>>>(W1, W2, fc1W, fc2W,
                                       W1th, W1tl, W2th, W2tl, f1th, f1tl, f2th, f2tl);
    binA<<<dim3(NT, 2), 256, 0, stream>>>(ba);
    binB1<<<dim3((NBK + 255) / 256, 2, 2), 256, 0, stream>>>(ba);
    binB2<<<dim3(1, 2, 2), 512, 0, stream>>>(ba);
    binB3<<<dim3((NBK + 63) / 64, 2, 2), 64, 0, stream>>>(ba);
    binC<<<dim3(NT, 2), 256, 0, stream>>>(ba);
    srchist<<<dim3(NBK, 2), 256, 0, stream>>>(ba);

    // ---- per-graph buffer aliases ----
    unsigned short *A1h[2], *A1l[2], *X1h[2], *X1l[2], *Gh[2], *Gl[2], *Zh[2], *Zl[2];
    float* T[2];
    for (int i = 0; i < 2; ++i) {
        A1h[i] = R1[i]; A1l[i] = R1[i] + (size_t)N * NDIM;
        T[i]   = (float*)R1[i];
        Zh[i]  = R1[i]; Zl[i]  = R1[i] + (size_t)N * NDIM;
        X1h[i] = R2[i]; X1l[i] = R2[i] + (size_t)N * H2;
        Gh[i]  = R2[i]; Gl[i]  = R2[i] + (size_t)N * NDIM;
    }

    // ---- gather1: A1 = split(gather(feat * ns)); computes nd ----
    GatherArgs ga = {};
    ga.n = N; ga.bias = b2;
    for (int i = 0; i < 2; ++i) {
        ga.X[i] = feat[i]; ga.pairs[i] = pairs_[i];
        ga.totD[i] = ba.totD[i]; ga.baseD[i] = ba.baseD[i];
        ga.ns[i] = ns_[i]; ga.nd[i] = nd_[i];
        ga.outH[i] = A1h[i]; ga.outL[i] = A1l[i];
    }
    gather_lds<1><<<dim3(NBK, 2), 1024, 0, stream>>>(ga);

    int mgrid = (N + 63) / 64;

    // ---- gemm1: X1 = relu(A1 @ W1 * nd + b1), split out ----
    GemmArgs g1 = {};
    g1.Bh = W1th; g1.Bl = W1tl; g1.bOut = b1;
    g1.M = N; g1.K = NDIM; g1.Nc = H2; g1.act = 1; g1.has_rs = 1; g1.has_b = 1; g1.split_out = 1;
    for (int i = 0; i < 2; ++i) {
        g1.Ah[i] = A1h[i]; g1.Al[i] = A1l[i];
        g1.CH[i] = X1h[i]; g1.CL[i] = X1l[i]; g1.rsOut[i] = nd_[i];
    }
    mfma_gemm_b<<<dim3(mgrid, H2 / 128, 2), 256, 0, stream>>>(g1);

    // ---- gemm2: T = X1 @ W2, fp32 out (matmul before aggregate) ----
    GemmArgs g2 = {};
    g2.Bh = W2th; g2.Bl = W2tl;
    g2.M = N; g2.K = H2; g2.Nc = NDIM; g2.act = 0; g2.has_rs = 0; g2.has_b = 0; g2.split_out = 0;
    for (int i = 0; i < 2; ++i) { g2.Ah[i] = X1h[i]; g2.Al[i] = X1l[i]; g2.C[i] = T[i]; }
    mfma_gemm_b<<<dim3(mgrid, 1, 2), 256, 0, stream>>>(g2);

    // ---- gather2: G = split(relu(gather(T * ns) * nd + b2)) ----
    GatherArgs gb = ga;
    for (int i = 0; i < 2; ++i) {
        gb.X[i] = T[i];
        gb.outH[i] = Gh[i]; gb.outL[i] = Gl[i];
    }
    gather_lds<2><<<dim3(NBK, 2), 1024, 0, stream>>>(gb);

    // ---- gemm3: Z = elu(G @ fc1W + fc1b), split out ----
    GemmArgs g3 = {};
    g3.Bh = f1th; g3.Bl = f1tl; g3.bOut = fc1b;
    g3.M = N; g3.K = NDIM; g3.Nc = NDIM; g3.act = 2; g3.has_rs = 0; g3.has_b = 1; g3.split_out = 1;
    for (int i = 0; i < 2; ++i) {
        g3.Ah[i] = Gh[i]; g3.Al[i] = Gl[i];
        g3.CH[i] = Zh[i]; g3.CL[i] = Zl[i];
    }
    mfma_gemm_b<<<dim3(mgrid, 1, 2), 256, 0, stream>>>(g3);

    // ---- gemm4: out = Z @ fc2W + fc2b, fp32 out ----
    GemmArgs g4 = {};
    g4.Bh = f2th; g4.Bl = f2tl; g4.bOut = fc2b;
    g4.M = N; g4.K = NDIM; g4.Nc = NDIM; g4.act = 0; g4.has_rs = 0; g4.has_b = 1; g4.split_out = 0;
    for (int i = 0; i < 2; ++i) {
        g4.Ah[i] = Zh[i]; g4.Al[i] = Zl[i];
        g4.C[i] = out + (size_t)i * N * NDIM;
    }
    mfma_gemm_b<<<dim3(mgrid, 1, 2), 256, 0, stream>>>(g4);
}

// Round 6
// 636.091 us; speedup vs baseline: 4.8172x; 4.8172x over previous
//
#include <hip/hip_runtime.h>
#include <math.h>

#define NDIM 128   // in_dim = hid = out_dim
#define H2   256   // 2*hid
#define MAXG 2
#define TPE  8192  // edges per bin tile
#define NBKMAX 512 // max buckets (N <= 65536, 128 nodes/bucket)

typedef __attribute__((ext_vector_type(8))) short bf16x8;
typedef __attribute__((ext_vector_type(4))) float f32x4;

__device__ __forceinline__ unsigned short f2bf(float f) {
    unsigned int u = __float_as_uint(f);
    u += 0x7fffu + ((u >> 16) & 1u);           // RNE
    return (unsigned short)(u >> 16);
}
__device__ __forceinline__ float bf2f(unsigned short h) {
    return __uint_as_float(((unsigned int)h) << 16);
}
__device__ __forceinline__ void split2(float f, unsigned short& h, unsigned short& l) {
    h = f2bf(f);
    l = f2bf(f - bf2f(h));
}

// ================= binned edge build (no global atomics) =================
struct BinArgs {
    const int* src[MAXG]; const int* dst[MAXG];
    int* histD[MAXG]; int* histS[MAXG];     // [NT][NBK] counts -> global run offsets
    int* totD[MAXG];  int* baseD[MAXG];
    int* totS[MAXG];  int* baseS[MAXG];
    unsigned int* pairs[MAXG];              // dst-binned packed (dl<<16|src)
    unsigned short* srcS[MAXG];             // src-binned bare src ids
    float* ns[MAXG];
    int E[MAXG]; int NBK; int NT; int n;
};

__global__ __launch_bounds__(256) void binA(BinArgs a) {
    __shared__ int cntD[NBKMAX], cntS[NBKMAX];
    int g = blockIdx.y, t = blockIdx.x, tid = threadIdx.x;
    for (int b = tid; b < NBKMAX; b += 256) { cntD[b] = 0; cntS[b] = 0; }
    __syncthreads();
    int E = a.E[g];
    int base = t * TPE;
#pragma unroll
    for (int k = 0; k < TPE / 256; ++k) {
        int e = base + k * 256 + tid;
        if (e < E) {
            atomicAdd(&cntD[a.dst[g][e] >> 7], 1);
            atomicAdd(&cntS[a.src[g][e] >> 7], 1);
        }
    }
    __syncthreads();
    for (int b = tid; b < a.NBK; b += 256) {
        a.histD[g][t * a.NBK + b] = cntD[b];
        a.histS[g][t * a.NBK + b] = cntS[b];
    }
}

__global__ void binB1(BinArgs a) {
    int g = blockIdx.y, side = blockIdx.z;
    int b = blockIdx.x * 256 + threadIdx.x;
    if (b >= a.NBK) return;
    const int* hist = side ? a.histS[g] : a.histD[g];
    int s = 0;
    for (int t = 0; t < a.NT; ++t) s += hist[t * a.NBK + b];
    (side ? a.totS[g] : a.totD[g])[b] = s;
}

__global__ __launch_bounds__(512) void binB2(BinArgs a) {
    int g = blockIdx.y, side = blockIdx.z;
    __shared__ int s[512];
    int t = threadIdx.x;
    const int* tot = side ? a.totS[g] : a.totD[g];
    int v = (t < a.NBK) ? tot[t] : 0;
    s[t] = v;
    __syncthreads();
    for (int off = 1; off < 512; off <<= 1) {
        int u = (t >= off) ? s[t - off] : 0;
        __syncthreads();
        s[t] += u;
        __syncthreads();
    }
    if (t < a.NBK) (side ? a.baseS[g] : a.baseD[g])[t] = s[t] - v;
}

__global__ void binB3(BinArgs a) {
    int g = blockIdx.y, side = blockIdx.z;
    int b = blockIdx.x * 64 + threadIdx.x;
    if (b >= a.NBK) return;
    int* hist = side ? a.histS[g] : a.histD[g];
    int run = (side ? a.baseS[g] : a.baseD[g])[b];
    for (int t = 0; t < a.NT; ++t) {
        int v = hist[t * a.NBK + b];
        hist[t * a.NBK + b] = run;
        run += v;
    }
}

__global__ __launch_bounds__(256) void binC(BinArgs a) {
    __shared__ int offD[NBKMAX], offS[NBKMAX];
    int g = blockIdx.y, t = blockIdx.x, tid = threadIdx.x;
    for (int b = tid; b < a.NBK; b += 256) {
        offD[b] = a.histD[g][t * a.NBK + b];
        offS[b] = a.histS[g][t * a.NBK + b];
    }
    __syncthreads();
    int E = a.E[g];
    int base = t * TPE;
    unsigned int* pairs = a.pairs[g];
    unsigned short* ss = a.srcS[g];
#pragma unroll
    for (int k = 0; k < TPE / 256; ++k) {
        int e = base + k * 256 + tid;
        if (e < E) {
            int s = a.src[g][e], d = a.dst[g][e];
            int pos = atomicAdd(&offD[d >> 7], 1);
            pairs[pos] = ((unsigned int)(d & 127) << 16) | (unsigned int)s;
            int posS = atomicAdd(&offS[s >> 7], 1);
            ss[posS] = (unsigned short)s;
        }
    }
}

// exact out-degree per node via per-bucket LDS histogram -> norm_src
__global__ __launch_bounds__(256) void srchist(BinArgs a) {
    __shared__ int cnt[128];
    int g = blockIdx.y, b = blockIdx.x, tid = threadIdx.x;
    if (tid < 128) cnt[tid] = 0;
    __syncthreads();
    int base = a.baseS[g][b], tot = a.totS[g][b];
    const unsigned short* ss = a.srcS[g];
    for (int i = tid; i < tot; i += 256)
        atomicAdd(&cnt[ss[base + i] & 127], 1);
    __syncthreads();
    if (tid < 128) {
        int node = b * 128 + tid;
        if (node < a.n) {
            int c = cnt[tid];
            a.ns[g][node] = rsqrtf((float)(c > 1 ? c : 1));
        }
    }
}

// ===== bucket_sort: per-bucket LDS counting sort -> exact per-node CSR + nd =====
// Two passes over the bucket segment; only 128 LDS int counters; writes stay in an
// ~8KB L2-resident window (no 64B-line write amplification like global fill).
struct SortArgs {
    const unsigned int* pairs[MAXG];
    const int* totD[MAXG]; const int* baseD[MAXG];
    int* row_ptr[MAXG]; int* row_end[MAXG];
    int* edge_srt[MAXG];
    float* nd[MAXG];
    int n;
};

__global__ __launch_bounds__(256) void bucket_sort(SortArgs a) {
    __shared__ int hist[128], scan[128], cur[128];
    int g = blockIdx.y, bkt = blockIdx.x, tid = threadIdx.x;
    if (tid < 128) hist[tid] = 0;
    __syncthreads();
    int cnt = a.totD[g][bkt], base = a.baseD[g][bkt];
    const unsigned int* pp = a.pairs[g] + base;
    for (int i = tid; i < cnt; i += 256) atomicAdd(&hist[pp[i] >> 16], 1);
    __syncthreads();
    if (tid < 128) scan[tid] = hist[tid];
    __syncthreads();
    for (int off = 1; off < 128; off <<= 1) {
        int v = (tid < 128 && tid >= off) ? scan[tid - off] : 0;
        __syncthreads();
        if (tid < 128) scan[tid] += v;
        __syncthreads();
    }
    if (tid < 128) {
        int incl = scan[tid];
        int h = hist[tid];
        cur[tid] = incl - h;
        int node = bkt * 128 + tid;
        if (node < a.n) {
            a.row_ptr[g][node] = base + incl - h;
            a.row_end[g][node] = base + incl;
            a.nd[g][node] = rsqrtf((float)(h > 1 ? h : 1));
        }
    }
    __syncthreads();
    for (int i = tid; i < cnt; i += 256) {
        unsigned int p = pp[i];
        int pos = atomicAdd(&cur[p >> 16], 1);
        a.edge_srt[g][base + pos] = (int)(p & 0xFFFF);
    }
}

// ===== gather-aggregate (register accumulate), half-wave/row, float4, 4-deep =====
struct GatherArgs {
    const float* X[MAXG];
    const int* row_ptr[MAXG]; const int* row_end[MAXG]; const int* edge_src[MAXG];
    const float* ns[MAXG]; const float* nd[MAXG];
    unsigned short* outH[MAXG]; unsigned short* outL[MAXG];
    const float* bias; int use_nd; int relu_on; int n;
};

__global__ __launch_bounds__(256) void gather_split_b(GatherArgs a) {
    int g = blockIdx.y;
    int half = threadIdx.x >> 5;
    int lane = threadIdx.x & 31;
    int r = blockIdx.x * 8 + half;
    if (r >= a.n) return;
    int j = a.row_ptr[g][r];
    int end = a.row_end[g][r];
    const int* ep = a.edge_src[g];
    const float* X = a.X[g];
    const float* rs = a.ns[g];
    int base = lane * 4;
    float4 acc = make_float4(0.f, 0.f, 0.f, 0.f);
    for (; j + 3 < end; j += 4) {
        int s0 = ep[j], s1 = ep[j + 1], s2 = ep[j + 2], s3 = ep[j + 3];
        float c0 = rs[s0], c1 = rs[s1], c2 = rs[s2], c3 = rs[s3];
        float4 v0 = *(const float4*)(X + (size_t)s0 * NDIM + base);
        float4 v1 = *(const float4*)(X + (size_t)s1 * NDIM + base);
        float4 v2 = *(const float4*)(X + (size_t)s2 * NDIM + base);
        float4 v3 = *(const float4*)(X + (size_t)s3 * NDIM + base);
        acc.x += v0.x * c0 + v1.x * c1 + v2.x * c2 + v3.x * c3;
        acc.y += v0.y * c0 + v1.y * c1 + v2.y * c2 + v3.y * c3;
        acc.z += v0.z * c0 + v1.z * c1 + v2.z * c2 + v3.z * c3;
        acc.w += v0.w * c0 + v1.w * c1 + v2.w * c2 + v3.w * c3;
    }
    for (; j < end; ++j) {
        int s0 = ep[j];
        float c0 = rs[s0];
        float4 v0 = *(const float4*)(X + (size_t)s0 * NDIM + base);
        acc.x += v0.x * c0; acc.y += v0.y * c0;
        acc.z += v0.z * c0; acc.w += v0.w * c0;
    }
    float v[4] = {acc.x, acc.y, acc.z, acc.w};
    if (a.use_nd) {
        float s = a.nd[g][r];
#pragma unroll
        for (int i = 0; i < 4; ++i) {
            v[i] = v[i] * s + a.bias[base + i];
            if (a.relu_on) v[i] = fmaxf(v[i], 0.f);
        }
    }
    unsigned short h[4], l[4];
#pragma unroll
    for (int i = 0; i < 4; ++i) split2(v[i], h[i], l[i]);
    *(ushort4*)(a.outH[g] + (size_t)r * NDIM + base) = make_ushort4(h[0], h[1], h[2], h[3]);
    *(ushort4*)(a.outL[g] + (size_t)r * NDIM + base) = make_ushort4(l[0], l[1], l[2], l[3]);
}

// ================= weight prep: all 4 weights, transposed + split =================
__global__ void wprep_all(const float* __restrict__ W1, const float* __restrict__ W2,
                          const float* __restrict__ F1, const float* __restrict__ F2,
                          unsigned short* __restrict__ W1h, unsigned short* __restrict__ W1l,
                          unsigned short* __restrict__ W2h, unsigned short* __restrict__ W2l,
                          unsigned short* __restrict__ F1h, unsigned short* __restrict__ F1l,
                          unsigned short* __restrict__ F2h, unsigned short* __restrict__ F2l) {
    int i = blockIdx.x * 256 + threadIdx.x;
    const float* Wsrc; unsigned short *Hd, *Ld; int K, Nc, idx;
    if (i < 32768)       { Wsrc = W1; Hd = W1h; Ld = W1l; K = 128; Nc = 256; idx = i; }
    else if (i < 65536)  { Wsrc = W2; Hd = W2h; Ld = W2l; K = 256; Nc = 128; idx = i - 32768; }
    else if (i < 81920)  { Wsrc = F1; Hd = F1h; Ld = F1l; K = 128; Nc = 128; idx = i - 65536; }
    else                 { Wsrc = F2; Hd = F2h; Ld = F2l; K = 128; Nc = 128; idx = i - 81920; }
    int k = idx / Nc, n = idx % Nc;
    unsigned short h, l;
    split2(Wsrc[idx], h, l);
    Hd[n * K + k] = h;
    Ld[n * K + k] = l;
}

// ================= split-bf16 MFMA GEMM (batched via blockIdx.z) =================
struct GemmArgs {
    const unsigned short* Ah[MAXG]; const unsigned short* Al[MAXG];
    const unsigned short* Bh; const unsigned short* Bl;
    float* C[MAXG]; unsigned short* CH[MAXG]; unsigned short* CL[MAXG];
    const float* rsOut[MAXG]; const float* bOut;
    int M, K, Nc, act, has_rs, has_b, split_out;
};

__global__ __launch_bounds__(256) void mfma_gemm_b(GemmArgs a) {
    __shared__ __align__(16) unsigned short Ah[64 * 40];
    __shared__ __align__(16) unsigned short Al[64 * 40];
    __shared__ __align__(16) unsigned short Bh[128 * 40];
    __shared__ __align__(16) unsigned short Bl[128 * 40];

    int g = blockIdx.z;
    const unsigned short* Ah_g = a.Ah[g];
    const unsigned short* Al_g = a.Al[g];

    int tid  = threadIdx.x;
    int wave = tid >> 6, lane = tid & 63;
    int quad = lane >> 4, l16 = lane & 15;
    int rowBase = blockIdx.x * 64;
    int colBase = blockIdx.y * 128;
    int M = a.M, K = a.K, Nc = a.Nc;

    f32x4 acc[4][2] = {};

    int s_row   = tid >> 2;
    int s_chunk = (tid & 3) * 8;

    for (int k0 = 0; k0 < K; k0 += 32) {
        int gr = rowBase + s_row;
        uint4 va_h = make_uint4(0, 0, 0, 0), va_l = make_uint4(0, 0, 0, 0);
        if (gr < M) {
            va_h = *(const uint4*)(Ah_g + (size_t)gr * K + k0 + s_chunk);
            va_l = *(const uint4*)(Al_g + (size_t)gr * K + k0 + s_chunk);
        }
        *(uint4*)(Ah + s_row * 40 + s_chunk) = va_h;
        *(uint4*)(Al + s_row * 40 + s_chunk) = va_l;
#pragma unroll
        for (int c = tid; c < 512; c += 256) {
            int bn = c >> 2, bc = (c & 3) * 8;
            uint4 vb_h = *(const uint4*)(a.Bh + (size_t)(colBase + bn) * K + k0 + bc);
            uint4 vb_l = *(const uint4*)(a.Bl + (size_t)(colBase + bn) * K + k0 + bc);
            *(uint4*)(Bh + bn * 40 + bc) = vb_h;
            *(uint4*)(Bl + bn * 40 + bc) = vb_l;
        }
        __syncthreads();

        bf16x8 af[4], alf[4], bhf[2], blf[2];
#pragma unroll
        for (int i = 0; i < 4; ++i) {
            af[i]  = *(const bf16x8*)(Ah + (i * 16 + l16) * 40 + quad * 8);
            alf[i] = *(const bf16x8*)(Al + (i * 16 + l16) * 40 + quad * 8);
        }
#pragma unroll
        for (int j = 0; j < 2; ++j) {
            bhf[j] = *(const bf16x8*)(Bh + (wave * 32 + j * 16 + l16) * 40 + quad * 8);
            blf[j] = *(const bf16x8*)(Bl + (wave * 32 + j * 16 + l16) * 40 + quad * 8);
        }
#pragma unroll
        for (int i = 0; i < 4; ++i)
#pragma unroll
            for (int j = 0; j < 2; ++j) {
                acc[i][j] = __builtin_amdgcn_mfma_f32_16x16x32_bf16(af[i],  bhf[j], acc[i][j], 0, 0, 0);
                acc[i][j] = __builtin_amdgcn_mfma_f32_16x16x32_bf16(alf[i], bhf[j], acc[i][j], 0, 0, 0);
                acc[i][j] = __builtin_amdgcn_mfma_f32_16x16x32_bf16(af[i],  blf[j], acc[i][j], 0, 0, 0);
            }
        __syncthreads();
    }

    // epilogue: C/D layout col=lane&15, row=quad*4+reg
#pragma unroll
    for (int i = 0; i < 4; ++i) {
#pragma unroll
        for (int r = 0; r < 4; ++r) {
            int row = rowBase + i * 16 + quad * 4 + r;
            if (row >= M) continue;
            float rs = a.has_rs ? a.rsOut[g][row] : 1.0f;
#pragma unroll
            for (int j = 0; j < 2; ++j) {
                int col = colBase + wave * 32 + j * 16 + l16;
                float v = acc[i][j][r] * rs;
                if (a.has_b) v += a.bOut[col];
                if (a.act == 1) v = fmaxf(v, 0.f);
                else if (a.act == 2) v = v > 0.f ? v : expm1f(v);
                if (a.split_out) {
                    unsigned short h, l;
                    split2(v, h, l);
                    a.CH[g][(size_t)row * Nc + col] = h;
                    a.CL[g][(size_t)row * Nc + col] = l;
                } else {
                    a.C[g][(size_t)row * Nc + col] = v;
                }
            }
        }
    }
}

extern "C" void kernel_launch(void* const* d_in, const int* in_sizes, int n_in,
                              void* d_out, int out_size, void* d_ws, size_t ws_size,
                              hipStream_t stream) {
    const float* feat[2] = {(const float*)d_in[0], (const float*)d_in[1]};
    const int*   ei[2]   = {(const int*)d_in[2], (const int*)d_in[3]};
    const float* W1   = (const float*)d_in[4];
    const float* b1   = (const float*)d_in[5];
    const float* W2   = (const float*)d_in[6];
    const float* b2   = (const float*)d_in[7];
    const float* fc1W = (const float*)d_in[8];
    const float* fc1b = (const float*)d_in[9];
    const float* fc2W = (const float*)d_in[10];
    const float* fc2b = (const float*)d_in[11];
    int N = in_sizes[0] / NDIM;     // 50000 (< 65536: u16 node-id packing valid)
    float* out = (float*)d_out;

    int Emax = 0;
    for (int g = 0; g < 2; ++g) { int E = in_sizes[2 + g] / 2; if (E > Emax) Emax = E; }
    int NBK = (N + 127) / 128;
    int NT  = (Emax + TPE - 1) / TPE;

    // ---- workspace layout ----
    char* p = (char*)d_ws;
    float* ns_[2]; float* nd_[2];
    for (int i = 0; i < 2; ++i) { ns_[i] = (float*)p; p += (size_t)N * 4; }
    for (int i = 0; i < 2; ++i) { nd_[i] = (float*)p; p += (size_t)N * 4; }
    int* rp_[2]; int* re_[2]; int* esrt_[2];
    for (int i = 0; i < 2; ++i) { rp_[i] = (int*)p; p += (size_t)N * 4; }
    for (int i = 0; i < 2; ++i) { re_[i] = (int*)p; p += (size_t)N * 4; }
    for (int i = 0; i < 2; ++i) { esrt_[i] = (int*)p; p += (size_t)Emax * 4; }
    unsigned short* R1[2]; unsigned short* R2[2];
    for (int i = 0; i < 2; ++i) { R1[i] = (unsigned short*)p; p += (size_t)N * NDIM * 2 * 2; }
    for (int i = 0; i < 2; ++i) { R2[i] = (unsigned short*)p; p += (size_t)N * H2 * 2 * 2; }
    unsigned short* W1th = (unsigned short*)p; p += (size_t)NDIM * H2 * 2;
    unsigned short* W1tl = (unsigned short*)p; p += (size_t)NDIM * H2 * 2;
    unsigned short* W2th = (unsigned short*)p; p += (size_t)H2 * NDIM * 2;
    unsigned short* W2tl = (unsigned short*)p; p += (size_t)H2 * NDIM * 2;
    unsigned short* f1th = (unsigned short*)p; p += (size_t)NDIM * NDIM * 2;
    unsigned short* f1tl = (unsigned short*)p; p += (size_t)NDIM * NDIM * 2;
    unsigned short* f2th = (unsigned short*)p; p += (size_t)NDIM * NDIM * 2;
    unsigned short* f2tl = (unsigned short*)p; p += (size_t)NDIM * NDIM * 2;
    int* tb = (int*)p; p += (size_t)2 * 4 * NBK * 4;   // totD/baseD/totS/baseS per graph

    // aliases with disjoint lifetimes:
    //  - hist tables + pairs live in R2 (dead before gemm1 writes X1)
    //  - srcS lives in R1 (dead after srchist; gather1 then writes A1)
    int* histD_[2]; int* histS_[2]; unsigned int* pairs_[2]; unsigned short* srcS_[2];
    for (int i = 0; i < 2; ++i) {
        histD_[i] = (int*)R2[i];
        histS_[i] = (int*)R2[i] + (size_t)NT * NBK;
        pairs_[i] = (unsigned int*)((char*)R2[i] + (1 << 20));  // 1MB offset > hist tables
        srcS_[i]  = (unsigned short*)R1[i];
    }

    BinArgs ba = {};
    ba.NBK = NBK; ba.NT = NT; ba.n = N;
    for (int i = 0; i < 2; ++i) {
        int E = in_sizes[2 + i] / 2;
        ba.src[i] = ei[i]; ba.dst[i] = ei[i] + E; ba.E[i] = E;
        ba.histD[i] = histD_[i]; ba.histS[i] = histS_[i];
        ba.totD[i]  = tb + (size_t)i * 4 * NBK;
        ba.baseD[i] = tb + (size_t)i * 4 * NBK + NBK;
        ba.totS[i]  = tb + (size_t)i * 4 * NBK + 2 * NBK;
        ba.baseS[i] = tb + (size_t)i * 4 * NBK + 3 * NBK;
        ba.pairs[i] = pairs_[i]; ba.srcS[i] = srcS_[i];
        ba.ns[i] = ns_[i];
    }

    // ---- weight prep + binned edge build ----
    wprep_all<<<384, 256, 0, stream>>>(W1, W2, fc1W, fc2W,
                                       W1th, W1tl, W2th, W2tl, f1th, f1tl, f2th, f2tl);
    binA<<<dim3(NT, 2), 256, 0, stream>>>(ba);
    binB1<<<dim3((NBK + 255) / 256, 2, 2), 256, 0, stream>>>(ba);
    binB2<<<dim3(1, 2, 2), 512, 0, stream>>>(ba);
    binB3<<<dim3((NBK + 63) / 64, 2, 2), 64, 0, stream>>>(ba);
    binC<<<dim3(NT, 2), 256, 0, stream>>>(ba);
    srchist<<<dim3(NBK, 2), 256, 0, stream>>>(ba);

    SortArgs sa = {};
    sa.n = N;
    for (int i = 0; i < 2; ++i) {
        sa.pairs[i] = pairs_[i];
        sa.totD[i] = ba.totD[i]; sa.baseD[i] = ba.baseD[i];
        sa.row_ptr[i] = rp_[i]; sa.row_end[i] = re_[i];
        sa.edge_srt[i] = esrt_[i]; sa.nd[i] = nd_[i];
    }
    bucket_sort<<<dim3(NBK, 2), 256, 0, stream>>>(sa);

    // ---- per-graph buffer aliases ----
    unsigned short *A1h[2], *A1l[2], *X1h[2], *X1l[2], *Gh[2], *Gl[2], *Zh[2], *Zl[2];
    float* T[2];
    for (int i = 0; i < 2; ++i) {
        A1h[i] = R1[i]; A1l[i] = R1[i] + (size_t)N * NDIM;
        T[i]   = (float*)R1[i];
        Zh[i]  = R1[i]; Zl[i]  = R1[i] + (size_t)N * NDIM;
        X1h[i] = R2[i]; X1l[i] = R2[i] + (size_t)N * H2;
        Gh[i]  = R2[i]; Gl[i]  = R2[i] + (size_t)N * NDIM;
    }

    int ggrid = (N + 7) / 8;
    int mgrid = (N + 63) / 64;

    // ---- gather1: A1 = split(gather(feat * ns)) ----
    GatherArgs ga = {};
    ga.n = N; ga.use_nd = 0; ga.relu_on = 0; ga.bias = b2;
    for (int i = 0; i < 2; ++i) {
        ga.X[i] = feat[i];
        ga.row_ptr[i] = rp_[i]; ga.row_end[i] = re_[i]; ga.edge_src[i] = esrt_[i];
        ga.ns[i] = ns_[i]; ga.nd[i] = nd_[i];
        ga.outH[i] = A1h[i]; ga.outL[i] = A1l[i];
    }
    gather_split_b<<<dim3(ggrid, 2), 256, 0, stream>>>(ga);

    // ---- gemm1: X1 = relu(A1 @ W1 * nd + b1), split out ----
    GemmArgs g1 = {};
    g1.Bh = W1th; g1.Bl = W1tl; g1.bOut = b1;
    g1.M = N; g1.K = NDIM; g1.Nc = H2; g1.act = 1; g1.has_rs = 1; g1.has_b = 1; g1.split_out = 1;
    for (int i = 0; i < 2; ++i) {
        g1.Ah[i] = A1h[i]; g1.Al[i] = A1l[i];
        g1.CH[i] = X1h[i]; g1.CL[i] = X1l[i]; g1.rsOut[i] = nd_[i];
    }
    mfma_gemm_b<<<dim3(mgrid, H2 / 128, 2), 256, 0, stream>>>(g1);

    // ---- gemm2: T = X1 @ W2, fp32 out (matmul before aggregate) ----
    GemmArgs g2 = {};
    g2.Bh = W2th; g2.Bl = W2tl;
    g2.M = N; g2.K = H2; g2.Nc = NDIM; g2.act = 0; g2.has_rs = 0; g2.has_b = 0; g2.split_out = 0;
    for (int i = 0; i < 2; ++i) { g2.Ah[i] = X1h[i]; g2.Al[i] = X1l[i]; g2.C[i] = T[i]; }
    mfma_gemm_b<<<dim3(mgrid, 1, 2), 256, 0, stream>>>(g2);

    // ---- gather2: G = split(relu(gather(T * ns) * nd + b2)) ----
    GatherArgs gb = ga;
    gb.use_nd = 1; gb.relu_on = 1;
    for (int i = 0; i < 2; ++i) {
        gb.X[i] = T[i];
        gb.outH[i] = Gh[i]; gb.outL[i] = Gl[i];
    }
    gather_split_b<<<dim3(ggrid, 2), 256, 0, stream>>>(gb);

    // ---- gemm3: Z = elu(G @ fc1W + fc1b), split out ----
    GemmArgs g3 = {};
    g3.Bh = f1th; g3.Bl = f1tl; g3.bOut = fc1b;
    g3.M = N; g3.K = NDIM; g3.Nc = NDIM; g3.act = 2; g3.has_rs = 0; g3.has_b = 1; g3.split_out = 1;
    for (int i = 0; i < 2; ++i) {
        g3.Ah[i] = Gh[i]; g3.Al[i] = Gl[i];
        g3.CH[i] = Zh[i]; g3.CL[i] = Zl[i];
    }
    mfma_gemm_b<<<dim3(mgrid, 1, 2), 256, 0, stream>>>(g3);

    // ---- gemm4: out = Z @ fc2W + fc2b, fp32 out ----
    GemmArgs g4 = {};
    g4.Bh = f2th; g4.Bl = f2tl; g4.bOut = fc2b;
    g4.M = N; g4.K = NDIM; g4.Nc = NDIM; g4.act = 0; g4.has_rs = 0; g4.has_b = 1; g4.split_out = 0;
    for (int i = 0; i < 2; ++i) {
        g4.Ah[i] = Zh[i]; g4.Al[i] = Zl[i];
        g4.C[i] = out + (size_t)i * N * NDIM;
    }
    mfma_gemm_b<<<dim3(mgrid, 1, 2), 256, 0, stream>>>(g4);
}

// Round 7
// 633.870 us; speedup vs baseline: 4.8341x; 1.0035x over previous
//
#include <hip/hip_runtime.h>
#include <math.h>

#define NDIM 128   // in_dim = hid = out_dim
#define H2   256   // 2*hid
#define MAXG 2
#define TPE  8192  // edges per bin tile
#define NBKMAX 512 // max buckets (N <= 65536, 128 nodes/bucket)

typedef __attribute__((ext_vector_type(8))) short bf16x8;
typedef __attribute__((ext_vector_type(4))) float f32x4;

__device__ __forceinline__ unsigned short f2bf(float f) {
    unsigned int u = __float_as_uint(f);
    u += 0x7fffu + ((u >> 16) & 1u);           // RNE
    return (unsigned short)(u >> 16);
}
__device__ __forceinline__ float bf2f(unsigned short h) {
    return __uint_as_float(((unsigned int)h) << 16);
}
__device__ __forceinline__ void split2(float f, unsigned short& h, unsigned short& l) {
    h = f2bf(f);
    l = f2bf(f - bf2f(h));
}

// ================= binned edge build (no global atomics) =================
struct BinArgs {
    const int* src[MAXG]; const int* dst[MAXG];
    int* histD[MAXG]; int* histS[MAXG];     // [NT][NBK] counts -> global run offsets
    int* totD[MAXG];  int* baseD[MAXG];
    int* totS[MAXG];  int* baseS[MAXG];
    unsigned int* pairs[MAXG];              // dst-binned packed (dl<<16|src)
    unsigned short* srcS[MAXG];             // src-binned bare src ids
    int E[MAXG]; int NBK; int NT; int n;
};

__global__ __launch_bounds__(256) void binA(BinArgs a) {
    __shared__ int cntD[NBKMAX], cntS[NBKMAX];
    int g = blockIdx.y, t = blockIdx.x, tid = threadIdx.x;
    for (int b = tid; b < NBKMAX; b += 256) { cntD[b] = 0; cntS[b] = 0; }
    __syncthreads();
    int E = a.E[g];
    int base = t * TPE;
#pragma unroll
    for (int k = 0; k < TPE / 256; ++k) {
        int e = base + k * 256 + tid;
        if (e < E) {
            atomicAdd(&cntD[a.dst[g][e] >> 7], 1);
            atomicAdd(&cntS[a.src[g][e] >> 7], 1);
        }
    }
    __syncthreads();
    for (int b = tid; b < a.NBK; b += 256) {
        a.histD[g][t * a.NBK + b] = cntD[b];
        a.histS[g][t * a.NBK + b] = cntS[b];
    }
}

// fused: per-bucket totals + exclusive scan + rewrite hist to global run offsets
__global__ __launch_bounds__(512) void binB(BinArgs a) {
    int g = blockIdx.y, side = blockIdx.z;
    int* hist = side ? a.histS[g] : a.histD[g];
    int* tot  = side ? a.totS[g]  : a.totD[g];
    int* base = side ? a.baseS[g] : a.baseD[g];
    __shared__ int s[512];
    int b = threadIdx.x;
    int v = 0;
    if (b < a.NBK)
        for (int t = 0; t < a.NT; ++t) v += hist[t * a.NBK + b];
    s[b] = v;
    __syncthreads();
    for (int off = 1; off < 512; off <<= 1) {
        int u = (b >= off) ? s[b - off] : 0;
        __syncthreads();
        s[b] += u;
        __syncthreads();
    }
    int excl = s[b] - v;
    if (b < a.NBK) {
        tot[b] = v;
        base[b] = excl;
        int run = excl;
        for (int t = 0; t < a.NT; ++t) {
            int h = hist[t * a.NBK + b];
            hist[t * a.NBK + b] = run;
            run += h;
        }
    }
}

__global__ __launch_bounds__(256) void binC(BinArgs a) {
    __shared__ int offD[NBKMAX], offS[NBKMAX];
    int g = blockIdx.y, t = blockIdx.x, tid = threadIdx.x;
    for (int b = tid; b < a.NBK; b += 256) {
        offD[b] = a.histD[g][t * a.NBK + b];
        offS[b] = a.histS[g][t * a.NBK + b];
    }
    __syncthreads();
    int E = a.E[g];
    int base = t * TPE;
    unsigned int* pairs = a.pairs[g];
    unsigned short* ss = a.srcS[g];
#pragma unroll
    for (int k = 0; k < TPE / 256; ++k) {
        int e = base + k * 256 + tid;
        if (e < E) {
            int s = a.src[g][e], d = a.dst[g][e];
            int pos = atomicAdd(&offD[d >> 7], 1);
            pairs[pos] = ((unsigned int)(d & 127) << 16) | (unsigned int)s;
            int posS = atomicAdd(&offS[s >> 7], 1);
            ss[posS] = (unsigned short)s;
        }
    }
}

// fused: out-degree hist (-> ns) + per-bucket counting sort (-> CSR, nd, u16 edges)
struct FinArgs {
    const unsigned int* pairs[MAXG];
    const unsigned short* srcS[MAXG];
    const int* totD[MAXG]; const int* baseD[MAXG];
    const int* totS[MAXG]; const int* baseS[MAXG];
    int* row_ptr[MAXG]; int* row_end[MAXG];
    unsigned short* edge_srt[MAXG];
    float* ns[MAXG]; float* nd[MAXG];
    int n;
};

__global__ __launch_bounds__(256) void finalize(FinArgs a) {
    __shared__ int cnt[128], hist[128], scn[128], cur[128];
    int g = blockIdx.y, bkt = blockIdx.x, tid = threadIdx.x;
    if (tid < 128) { cnt[tid] = 0; hist[tid] = 0; }
    __syncthreads();
    // --- out-degree from src-binned segment -> ns ---
    {
        int base = a.baseS[g][bkt], tot = a.totS[g][bkt];
        const unsigned short* ss = a.srcS[g];
        for (int i = tid; i < tot; i += 256)
            atomicAdd(&cnt[ss[base + i] & 127], 1);
    }
    // --- in-degree hist of dst-binned pairs ---
    int cntE = a.totD[g][bkt], base = a.baseD[g][bkt];
    const unsigned int* pp = a.pairs[g] + base;
    for (int i = tid; i < cntE; i += 256)
        atomicAdd(&hist[pp[i] >> 16], 1);
    __syncthreads();
    if (tid < 128) {
        int node = bkt * 128 + tid;
        if (node < a.n) {
            int c = cnt[tid];
            a.ns[g][node] = rsqrtf((float)(c > 1 ? c : 1));
        }
        scn[tid] = hist[tid];
    }
    __syncthreads();
    for (int off = 1; off < 128; off <<= 1) {
        int v = (tid < 128 && tid >= off) ? scn[tid - off] : 0;
        __syncthreads();
        if (tid < 128) scn[tid] += v;
        __syncthreads();
    }
    if (tid < 128) {
        int incl = scn[tid];
        int h = hist[tid];
        cur[tid] = incl - h;
        int node = bkt * 128 + tid;
        if (node < a.n) {
            a.row_ptr[g][node] = base + incl - h;
            a.row_end[g][node] = base + incl;
            a.nd[g][node] = rsqrtf((float)(h > 1 ? h : 1));
        }
    }
    __syncthreads();
    for (int i = tid; i < cntE; i += 256) {
        unsigned int p = pp[i];
        int pos = atomicAdd(&cur[p >> 16], 1);
        a.edge_srt[g][base + pos] = (unsigned short)(p & 0xFFFF);
    }
}

// ================= prescale: Xs = feat * ns[row] =================
struct PreArgs { const float* X[MAXG]; const float* ns[MAXG]; float* Xs[MAXG]; int n; };

__global__ __launch_bounds__(256) void prescale(PreArgs a) {
    int g = blockIdx.y;
    int i = blockIdx.x * 256 + threadIdx.x;   // float4 index
    if (i >= a.n * 32) return;
    int row = i >> 5;
    float s = a.ns[g][row];
    float4 v = ((const float4*)a.X[g])[i];
    v.x *= s; v.y *= s; v.z *= s; v.w *= s;
    ((float4*)a.Xs[g])[i] = v;
}

// ===== gather-aggregate (pure row-sum; X pre-scaled by ns), half-wave/row =====
struct GatherArgs {
    const float* X[MAXG];
    const int* row_ptr[MAXG]; const int* row_end[MAXG];
    const unsigned short* edge_src[MAXG];
    const float* nd[MAXG];
    unsigned short* outH[MAXG]; unsigned short* outL[MAXG];
    const float* bias; int use_nd; int n;
};

__global__ __launch_bounds__(256) void gather_split_b(GatherArgs a) {
    int g = blockIdx.y;
    int half = threadIdx.x >> 5;
    int lane = threadIdx.x & 31;
    int r = blockIdx.x * 8 + half;
    if (r >= a.n) return;
    int j = a.row_ptr[g][r];
    int end = a.row_end[g][r];
    const unsigned short* ep = a.edge_src[g];
    const float* X = a.X[g];
    int base = lane * 4;
    float4 acc = make_float4(0.f, 0.f, 0.f, 0.f);
    for (; j + 3 < end; j += 4) {
        int s0 = ep[j], s1 = ep[j + 1], s2 = ep[j + 2], s3 = ep[j + 3];
        float4 v0 = *(const float4*)(X + (size_t)s0 * NDIM + base);
        float4 v1 = *(const float4*)(X + (size_t)s1 * NDIM + base);
        float4 v2 = *(const float4*)(X + (size_t)s2 * NDIM + base);
        float4 v3 = *(const float4*)(X + (size_t)s3 * NDIM + base);
        acc.x += v0.x + v1.x + v2.x + v3.x;
        acc.y += v0.y + v1.y + v2.y + v3.y;
        acc.z += v0.z + v1.z + v2.z + v3.z;
        acc.w += v0.w + v1.w + v2.w + v3.w;
    }
    for (; j < end; ++j) {
        int s0 = ep[j];
        float4 v0 = *(const float4*)(X + (size_t)s0 * NDIM + base);
        acc.x += v0.x; acc.y += v0.y; acc.z += v0.z; acc.w += v0.w;
    }
    float v[4] = {acc.x, acc.y, acc.z, acc.w};
    if (a.use_nd) {
        float s = a.nd[g][r];
#pragma unroll
        for (int i = 0; i < 4; ++i)
            v[i] = fmaxf(v[i] * s + a.bias[base + i], 0.f);
    }
    unsigned short h[4], l[4];
#pragma unroll
    for (int i = 0; i < 4; ++i) split2(v[i], h[i], l[i]);
    *(ushort4*)(a.outH[g] + (size_t)r * NDIM + base) = make_ushort4(h[0], h[1], h[2], h[3]);
    *(ushort4*)(a.outL[g] + (size_t)r * NDIM + base) = make_ushort4(l[0], l[1], l[2], l[3]);
}

// ================= weight prep: all 4 weights, transposed + split =================
__global__ void wprep_all(const float* __restrict__ W1, const float* __restrict__ W2,
                          const float* __restrict__ F1, const float* __restrict__ F2,
                          unsigned short* __restrict__ W1h, unsigned short* __restrict__ W1l,
                          unsigned short* __restrict__ W2h, unsigned short* __restrict__ W2l,
                          unsigned short* __restrict__ F1h, unsigned short* __restrict__ F1l,
                          unsigned short* __restrict__ F2h, unsigned short* __restrict__ F2l) {
    int i = blockIdx.x * 256 + threadIdx.x;
    const float* Wsrc; unsigned short *Hd, *Ld; int K, Nc, idx;
    if (i < 32768)       { Wsrc = W1; Hd = W1h; Ld = W1l; K = 128; Nc = 256; idx = i; }
    else if (i < 65536)  { Wsrc = W2; Hd = W2h; Ld = W2l; K = 256; Nc = 128; idx = i - 32768; }
    else if (i < 81920)  { Wsrc = F1; Hd = F1h; Ld = F1l; K = 128; Nc = 128; idx = i - 65536; }
    else                 { Wsrc = F2; Hd = F2h; Ld = F2l; K = 128; Nc = 128; idx = i - 81920; }
    int k = idx / Nc, n = idx % Nc;
    unsigned short h, l;
    split2(Wsrc[idx], h, l);
    Hd[n * K + k] = h;
    Ld[n * K + k] = l;
}

// ================= split-bf16 MFMA GEMM (batched via blockIdx.z) =================
struct GemmArgs {
    const unsigned short* Ah[MAXG]; const unsigned short* Al[MAXG];
    const unsigned short* Bh; const unsigned short* Bl;
    float* C[MAXG]; unsigned short* CH[MAXG]; unsigned short* CL[MAXG];
    const float* rsOut[MAXG]; const float* bOut;
    int M, K, Nc, act, has_rs, has_b, split_out;
};

__global__ __launch_bounds__(256) void mfma_gemm_b(GemmArgs a) {
    __shared__ __align__(16) unsigned short Ah[64 * 40];
    __shared__ __align__(16) unsigned short Al[64 * 40];
    __shared__ __align__(16) unsigned short Bh[128 * 40];
    __shared__ __align__(16) unsigned short Bl[128 * 40];

    int g = blockIdx.z;
    const unsigned short* Ah_g = a.Ah[g];
    const unsigned short* Al_g = a.Al[g];

    int tid  = threadIdx.x;
    int wave = tid >> 6, lane = tid & 63;
    int quad = lane >> 4, l16 = lane & 15;
    int rowBase = blockIdx.x * 64;
    int colBase = blockIdx.y * 128;
    int M = a.M, K = a.K, Nc = a.Nc;

    f32x4 acc[4][2] = {};

    int s_row   = tid >> 2;
    int s_chunk = (tid & 3) * 8;

    for (int k0 = 0; k0 < K; k0 += 32) {
        int gr = rowBase + s_row;
        uint4 va_h = make_uint4(0, 0, 0, 0), va_l = make_uint4(0, 0, 0, 0);
        if (gr < M) {
            va_h = *(const uint4*)(Ah_g + (size_t)gr * K + k0 + s_chunk);
            va_l = *(const uint4*)(Al_g + (size_t)gr * K + k0 + s_chunk);
        }
        *(uint4*)(Ah + s_row * 40 + s_chunk) = va_h;
        *(uint4*)(Al + s_row * 40 + s_chunk) = va_l;
#pragma unroll
        for (int c = tid; c < 512; c += 256) {
            int bn = c >> 2, bc = (c & 3) * 8;
            uint4 vb_h = *(const uint4*)(a.Bh + (size_t)(colBase + bn) * K + k0 + bc);
            uint4 vb_l = *(const uint4*)(a.Bl + (size_t)(colBase + bn) * K + k0 + bc);
            *(uint4*)(Bh + bn * 40 + bc) = vb_h;
            *(uint4*)(Bl + bn * 40 + bc) = vb_l;
        }
        __syncthreads();

        bf16x8 af[4], alf[4], bhf[2], blf[2];
#pragma unroll
        for (int i = 0; i < 4; ++i) {
            af[i]  = *(const bf16x8*)(Ah + (i * 16 + l16) * 40 + quad * 8);
            alf[i] = *(const bf16x8*)(Al + (i * 16 + l16) * 40 + quad * 8);
        }
#pragma unroll
        for (int j = 0; j < 2; ++j) {
            bhf[j] = *(const bf16x8*)(Bh + (wave * 32 + j * 16 + l16) * 40 + quad * 8);
            blf[j] = *(const bf16x8*)(Bl + (wave * 32 + j * 16 + l16) * 40 + quad * 8);
        }
#pragma unroll
        for (int i = 0; i < 4; ++i)
#pragma unroll
            for (int j = 0; j < 2; ++j) {
                acc[i][j] = __builtin_amdgcn_mfma_f32_16x16x32_bf16(af[i],  bhf[j], acc[i][j], 0, 0, 0);
                acc[i][j] = __builtin_amdgcn_mfma_f32_16x16x32_bf16(alf[i], bhf[j], acc[i][j], 0, 0, 0);
                acc[i][j] = __builtin_amdgcn_mfma_f32_16x16x32_bf16(af[i],  blf[j], acc[i][j], 0, 0, 0);
            }
        __syncthreads();
    }

    // epilogue: C/D layout col=lane&15, row=quad*4+reg
#pragma unroll
    for (int i = 0; i < 4; ++i) {
#pragma unroll
        for (int r = 0; r < 4; ++r) {
            int row = rowBase + i * 16 + quad * 4 + r;
            if (row >= M) continue;
            float rs = a.has_rs ? a.rsOut[g][row] : 1.0f;
#pragma unroll
            for (int j = 0; j < 2; ++j) {
                int col = colBase + wave * 32 + j * 16 + l16;
                float v = acc[i][j][r] * rs;
                if (a.has_b) v += a.bOut[col];
                if (a.act == 1) v = fmaxf(v, 0.f);
                else if (a.act == 2) v = v > 0.f ? v : expm1f(v);
                if (a.split_out) {
                    unsigned short h, l;
                    split2(v, h, l);
                    a.CH[g][(size_t)row * Nc + col] = h;
                    a.CL[g][(size_t)row * Nc + col] = l;
                } else {
                    a.C[g][(size_t)row * Nc + col] = v;
                }
            }
        }
    }
}

extern "C" void kernel_launch(void* const* d_in, const int* in_sizes, int n_in,
                              void* d_out, int out_size, void* d_ws, size_t ws_size,
                              hipStream_t stream) {
    const float* feat[2] = {(const float*)d_in[0], (const float*)d_in[1]};
    const int*   ei[2]   = {(const int*)d_in[2], (const int*)d_in[3]};
    const float* W1   = (const float*)d_in[4];
    const float* b1   = (const float*)d_in[5];
    const float* W2   = (const float*)d_in[6];
    const float* b2   = (const float*)d_in[7];
    const float* fc1W = (const float*)d_in[8];
    const float* fc1b = (const float*)d_in[9];
    const float* fc2W = (const float*)d_in[10];
    const float* fc2b = (const float*)d_in[11];
    int N = in_sizes[0] / NDIM;     // 50000 (< 65536: u16 node-id packing valid)
    float* out = (float*)d_out;

    int Emax = 0;
    for (int g = 0; g < 2; ++g) { int E = in_sizes[2 + g] / 2; if (E > Emax) Emax = E; }
    int NBK = (N + 127) / 128;
    int NT  = (Emax + TPE - 1) / TPE;

    // ---- workspace layout ----
    char* p = (char*)d_ws;
    float* ns_[2]; float* nd_[2];
    for (int i = 0; i < 2; ++i) { ns_[i] = (float*)p; p += (size_t)N * 4; }
    for (int i = 0; i < 2; ++i) { nd_[i] = (float*)p; p += (size_t)N * 4; }
    int* rp_[2]; int* re_[2]; unsigned short* esrt_[2];
    for (int i = 0; i < 2; ++i) { rp_[i] = (int*)p; p += (size_t)N * 4; }
    for (int i = 0; i < 2; ++i) { re_[i] = (int*)p; p += (size_t)N * 4; }
    for (int i = 0; i < 2; ++i) { esrt_[i] = (unsigned short*)p; p += (size_t)Emax * 2; }
    unsigned short* R1[2]; unsigned short* R2[2];
    for (int i = 0; i < 2; ++i) { R1[i] = (unsigned short*)p; p += (size_t)N * NDIM * 2 * 2; }
    for (int i = 0; i < 2; ++i) { R2[i] = (unsigned short*)p; p += (size_t)N * H2 * 2 * 2; }
    unsigned short* W1th = (unsigned short*)p; p += (size_t)NDIM * H2 * 2;
    unsigned short* W1tl = (unsigned short*)p; p += (size_t)NDIM * H2 * 2;
    unsigned short* W2th = (unsigned short*)p; p += (size_t)H2 * NDIM * 2;
    unsigned short* W2tl = (unsigned short*)p; p += (size_t)H2 * NDIM * 2;
    unsigned short* f1th = (unsigned short*)p; p += (size_t)NDIM * NDIM * 2;
    unsigned short* f1tl = (unsigned short*)p; p += (size_t)NDIM * NDIM * 2;
    unsigned short* f2th = (unsigned short*)p; p += (size_t)NDIM * NDIM * 2;
    unsigned short* f2tl = (unsigned short*)p; p += (size_t)NDIM * NDIM * 2;
    int* tb = (int*)p; p += (size_t)2 * 4 * NBK * 4;   // totD/baseD/totS/baseS per graph

    // aliases with disjoint lifetimes (all within R1/R2):
    //  - histD/histS at R2[i]+0 (dead after binC); pairs at R2[i]+1MB (dead after finalize)
    //  - Xs at R2[i]+0 (written by prescale AFTER finalize, dead after gather1;
    //    gemm1 overwrites R2 with X1 only after gather1 completes)
    //  - srcS at R1[i] (dead after finalize; gather1 then writes A1 into R1)
    int* histD_[2]; int* histS_[2]; unsigned int* pairs_[2]; unsigned short* srcS_[2];
    float* Xs_[2];
    for (int i = 0; i < 2; ++i) {
        histD_[i] = (int*)R2[i];
        histS_[i] = (int*)R2[i] + (size_t)NT * NBK;
        pairs_[i] = (unsigned int*)((char*)R2[i] + (1 << 20));  // 1MB offset > hist tables
        srcS_[i]  = (unsigned short*)R1[i];
        Xs_[i]    = (float*)R2[i];
    }

    BinArgs ba = {};
    ba.NBK = NBK; ba.NT = NT; ba.n = N;
    for (int i = 0; i < 2; ++i) {
        int E = in_sizes[2 + i] / 2;
        ba.src[i] = ei[i]; ba.dst[i] = ei[i] + E; ba.E[i] = E;
        ba.histD[i] = histD_[i]; ba.histS[i] = histS_[i];
        ba.totD[i]  = tb + (size_t)i * 4 * NBK;
        ba.baseD[i] = tb + (size_t)i * 4 * NBK + NBK;
        ba.totS[i]  = tb + (size_t)i * 4 * NBK + 2 * NBK;
        ba.baseS[i] = tb + (size_t)i * 4 * NBK + 3 * NBK;
        ba.pairs[i] = pairs_[i]; ba.srcS[i] = srcS_[i];
    }

    // ---- weight prep + binned edge build ----
    wprep_all<<<384, 256, 0, stream>>>(W1, W2, fc1W, fc2W,
                                       W1th, W1tl, W2th, W2tl, f1th, f1tl, f2th, f2tl);
    binA<<<dim3(NT, 2), 256, 0, stream>>>(ba);
    binB<<<dim3(1, 2, 2), 512, 0, stream>>>(ba);
    binC<<<dim3(NT, 2), 256, 0, stream>>>(ba);

    FinArgs fa = {};
    fa.n = N;
    for (int i = 0; i < 2; ++i) {
        fa.pairs[i] = pairs_[i]; fa.srcS[i] = srcS_[i];
        fa.totD[i] = ba.totD[i]; fa.baseD[i] = ba.baseD[i];
        fa.totS[i] = ba.totS[i]; fa.baseS[i] = ba.baseS[i];
        fa.row_ptr[i] = rp_[i]; fa.row_end[i] = re_[i];
        fa.edge_srt[i] = esrt_[i];
        fa.ns[i] = ns_[i]; fa.nd[i] = nd_[i];
    }
    finalize<<<dim3(NBK, 2), 256, 0, stream>>>(fa);

    // ---- prescale: Xs = feat * ns ----
    PreArgs pa = {};
    pa.n = N;
    for (int i = 0; i < 2; ++i) { pa.X[i] = feat[i]; pa.ns[i] = ns_[i]; pa.Xs[i] = Xs_[i]; }
    prescale<<<dim3((N * 32 + 255) / 256, 2), 256, 0, stream>>>(pa);

    // ---- per-graph buffer aliases ----
    unsigned short *A1h[2], *A1l[2], *X1h[2], *X1l[2], *Gh[2], *Gl[2], *Zh[2], *Zl[2];
    float* T[2];
    for (int i = 0; i < 2; ++i) {
        A1h[i] = R1[i]; A1l[i] = R1[i] + (size_t)N * NDIM;
        T[i]   = (float*)R1[i];
        Zh[i]  = R1[i]; Zl[i]  = R1[i] + (size_t)N * NDIM;
        X1h[i] = R2[i]; X1l[i] = R2[i] + (size_t)N * H2;
        Gh[i]  = R2[i]; Gl[i]  = R2[i] + (size_t)N * NDIM;
    }

    int ggrid = (N + 7) / 8;
    int mgrid = (N + 63) / 64;

    // ---- gather1: A1 = split(sum Xs[src]) ----
    GatherArgs ga = {};
    ga.n = N; ga.use_nd = 0; ga.bias = b2;
    for (int i = 0; i < 2; ++i) {
        ga.X[i] = Xs_[i];
        ga.row_ptr[i] = rp_[i]; ga.row_end[i] = re_[i]; ga.edge_src[i] = esrt_[i];
        ga.nd[i] = nd_[i];
        ga.outH[i] = A1h[i]; ga.outL[i] = A1l[i];
    }
    gather_split_b<<<dim3(ggrid, 2), 256, 0, stream>>>(ga);

    // ---- gemm1: X1 = relu(A1 @ W1 * nd + b1), split out ----
    GemmArgs g1 = {};
    g1.Bh = W1th; g1.Bl = W1tl; g1.bOut = b1;
    g1.M = N; g1.K = NDIM; g1.Nc = H2; g1.act = 1; g1.has_rs = 1; g1.has_b = 1; g1.split_out = 1;
    for (int i = 0; i < 2; ++i) {
        g1.Ah[i] = A1h[i]; g1.Al[i] = A1l[i];
        g1.CH[i] = X1h[i]; g1.CL[i] = X1l[i]; g1.rsOut[i] = nd_[i];
    }
    mfma_gemm_b<<<dim3(mgrid, H2 / 128, 2), 256, 0, stream>>>(g1);

    // ---- gemm2: T = (X1 @ W2) * ns, fp32 out (ns folded here so gather2 is a pure sum) ----
    GemmArgs g2 = {};
    g2.Bh = W2th; g2.Bl = W2tl;
    g2.M = N; g2.K = H2; g2.Nc = NDIM; g2.act = 0; g2.has_rs = 1; g2.has_b = 0; g2.split_out = 0;
    for (int i = 0; i < 2; ++i) {
        g2.Ah[i] = X1h[i]; g2.Al[i] = X1l[i]; g2.C[i] = T[i]; g2.rsOut[i] = ns_[i];
    }
    mfma_gemm_b<<<dim3(mgrid, 1, 2), 256, 0, stream>>>(g2);

    // ---- gather2: G = split(relu(sum T[src] * nd + b2)) ----
    GatherArgs gb = ga;
    gb.use_nd = 1;
    for (int i = 0; i < 2; ++i) {
        gb.X[i] = T[i];
        gb.outH[i] = Gh[i]; gb.outL[i] = Gl[i];
    }
    gather_split_b<<<dim3(ggrid, 2), 256, 0, stream>>>(gb);

    // ---- gemm3: Z = elu(G @ fc1W + fc1b), split out ----
    GemmArgs g3 = {};
    g3.Bh = f1th; g3.Bl = f1tl; g3.bOut = fc1b;
    g3.M = N; g3.K = NDIM; g3.Nc = NDIM; g3.act = 2; g3.has_rs = 0; g3.has_b = 1; g3.split_out = 1;
    for (int i = 0; i < 2; ++i) {
        g3.Ah[i] = Gh[i]; g3.Al[i] = Gl[i];
        g3.CH[i] = Zh[i]; g3.CL[i] = Zl[i];
    }
    mfma_gemm_b<<<dim3(mgrid, 1, 2), 256, 0, stream>>>(g3);

    // ---- gemm4: out = Z @ fc2W + fc2b, fp32 out ----
    GemmArgs g4 = {};
    g4.Bh = f2th; g4.Bl = f2tl; g4.bOut = fc2b;
    g4.M = N; g4.K = NDIM; g4.Nc = NDIM; g4.act = 0; g4.has_rs = 0; g4.has_b = 1; g4.split_out = 0;
    for (int i = 0; i < 2; ++i) {
        g4.Ah[i] = Zh[i]; g4.Al[i] = Zl[i];
        g4.C[i] = out + (size_t)i * N * NDIM;
    }
    mfma_gemm_b<<<dim3(mgrid, 1, 2), 256, 0, stream>>>(g4);
}